// Round 4
// baseline (1350.954 us; speedup 1.0000x reference)
//
#include <hip/hip_runtime.h>
#include <hip/hip_bf16.h>

typedef __hip_bfloat16 bf16;

#define BB 8
#define NN 8192
#define DIM 256
#define HEAD 4
#define HD 64
#define RANK 64
#define BN (BB*NN)
#define NCHUNK 16   // chunks over n for kB/kD

__device__ __forceinline__ float b2f(bf16 v){ return __bfloat162float(v); }
__device__ __forceinline__ bf16 f2b(float v){ return __float2bfloat16(v); }

__device__ __forceinline__ float wave_max64(float v){
    #pragma unroll
    for(int off = 32; off; off >>= 1) v = fmaxf(v, __shfl_xor(v, off, 64));
    return v;
}
__device__ __forceinline__ float wave_sum64(float v){
    #pragma unroll
    for(int off = 32; off; off >>= 1) v += __shfl_xor(v, off, 64);
    return v;
}

// ---------------------------------------------------------------------------
// kA: per 16-row block: q = z@Wq+bq ; attn[bn,h,r] = (q . K[r,h,:])/8 (bf16->ws);
//     xv = x@Wv+bv (fp32 -> d_out, reused as scratch).
// ---------------------------------------------------------------------------
__global__ void __launch_bounds__(256) kA(
    const float* __restrict__ x, const float* __restrict__ z,
    const float* __restrict__ Wq, const float* __restrict__ bq,
    const float* __restrict__ Km, const float* __restrict__ Wv,
    const float* __restrict__ bv,
    bf16* __restrict__ attn, float* __restrict__ xv)
{
    __shared__ float buf[16][DIM];        // 16 KB: z rows, then x rows
    __shared__ float q_s[16][DIM];        // 16 KB
    __shared__ bf16  K_s[HEAD][HD][RANK]; // 32 KB, [h][d][r]

    const int t    = threadIdx.x;
    const int lane = t & 63;
    const int w    = t >> 6;
    const int bn0  = blockIdx.x * 16;
    const int c0   = lane * 4;   // output-column tile
    const int r0   = w * 4;      // row tile

    // stage K transposed: K global layout (r,h,d) fp32 -> K_s[h][d][r] bf16
    #pragma unroll 4
    for(int i = 0; i < 64; i++){
        int j = t + 256*i;           // 0..16383
        int r = j >> 8, h = (j >> 6) & 3, d = j & 63;
        K_s[h][d][r] = f2b(Km[j]);
    }
    // stage z rows (float4 loads)
    {
        const float4* zr = (const float4*)(z + (size_t)bn0 * DIM);
        #pragma unroll
        for(int ii = 0; ii < 4; ii++){
            int g = t + 256*ii;            // float4 index, 0..1023
            int row = g >> 6, col = (g & 63) * 4;
            *(float4*)&buf[row][col] = zr[g];
        }
    }
    __syncthreads();

    float acc[4][4];
    // ---- GEMM q ----
    {
        const float4* Wq4 = (const float4*)Wq;   // [k][lane] -> 4 cols
        const float4  bu  = ((const float4*)bq)[lane];
        #pragma unroll
        for(int ri = 0; ri < 4; ri++){ acc[ri][0]=bu.x; acc[ri][1]=bu.y; acc[ri][2]=bu.z; acc[ri][3]=bu.w; }
        for(int k = 0; k < DIM; k += 4){
            float wv[4][4];
            #pragma unroll
            for(int kk = 0; kk < 4; kk++){
                float4 u = Wq4[(size_t)(k+kk)*64 + lane];
                wv[kk][0]=u.x; wv[kk][1]=u.y; wv[kk][2]=u.z; wv[kk][3]=u.w;
            }
            #pragma unroll
            for(int ri = 0; ri < 4; ri++){
                float4 zv = *(const float4*)&buf[r0+ri][k];
                float zz[4] = {zv.x, zv.y, zv.z, zv.w};
                #pragma unroll
                for(int kk = 0; kk < 4; kk++){
                    #pragma unroll
                    for(int ci = 0; ci < 4; ci++)
                        acc[ri][ci] = fmaf(zz[kk], wv[kk][ci], acc[ri][ci]);
                }
            }
        }
        #pragma unroll
        for(int ri = 0; ri < 4; ri++)
            *(float4*)&q_s[r0+ri][c0] = make_float4(acc[ri][0],acc[ri][1],acc[ri][2],acc[ri][3]);
    }
    __syncthreads();

    // stage x rows into buf (overwrite z; safe after sync)
    {
        const float4* xr = (const float4*)(x + (size_t)bn0 * DIM);
        #pragma unroll
        for(int ii = 0; ii < 4; ii++){
            int g = t + 256*ii;
            int row = g >> 6, col = (g & 63) * 4;
            *(float4*)&buf[row][col] = xr[g];
        }
    }

    // ---- attn logits: wave w = head, lane = r ----
    {
        const int h = w;
        for(int i = 0; i < 16; i++){
            float a = 0.f;
            #pragma unroll
            for(int d = 0; d < HD; d += 4){
                float4 q4 = *(const float4*)&q_s[i][h*HD + d];
                a = fmaf(q4.x, b2f(K_s[h][d+0][lane]), a);
                a = fmaf(q4.y, b2f(K_s[h][d+1][lane]), a);
                a = fmaf(q4.z, b2f(K_s[h][d+2][lane]), a);
                a = fmaf(q4.w, b2f(K_s[h][d+3][lane]), a);
            }
            a *= 0.125f;  // 1/sqrt(64)
            attn[(size_t)((bn0+i)*HEAD + h)*RANK + lane] = f2b(a);
        }
    }
    __syncthreads();

    // ---- GEMM xv ----
    {
        const float4* Wv4 = (const float4*)Wv;
        const float4  bu  = ((const float4*)bv)[lane];
        #pragma unroll
        for(int ri = 0; ri < 4; ri++){ acc[ri][0]=bu.x; acc[ri][1]=bu.y; acc[ri][2]=bu.z; acc[ri][3]=bu.w; }
        for(int k = 0; k < DIM; k += 4){
            float wv[4][4];
            #pragma unroll
            for(int kk = 0; kk < 4; kk++){
                float4 u = Wv4[(size_t)(k+kk)*64 + lane];
                wv[kk][0]=u.x; wv[kk][1]=u.y; wv[kk][2]=u.z; wv[kk][3]=u.w;
            }
            #pragma unroll
            for(int ri = 0; ri < 4; ri++){
                float4 xvv = *(const float4*)&buf[r0+ri][k];
                float xx[4] = {xvv.x, xvv.y, xvv.z, xvv.w};
                #pragma unroll
                for(int kk = 0; kk < 4; kk++){
                    #pragma unroll
                    for(int ci = 0; ci < 4; ci++)
                        acc[ri][ci] = fmaf(xx[kk], wv[kk][ci], acc[ri][ci]);
                }
            }
        }
        #pragma unroll
        for(int ri = 0; ri < 4; ri++)
            ((float4*)xv)[(size_t)(bn0+r0+ri)*64 + lane] =
                make_float4(acc[ri][0],acc[ri][1],acc[ri][2],acc[ri][3]);
    }
}

// ---------------------------------------------------------------------------
// kB: partial online (max, sum-exp) over an n-chunk, per (b,h,r)
// ---------------------------------------------------------------------------
__global__ void __launch_bounds__(256) kB(const bf16* __restrict__ attn,
                                          float* __restrict__ Pm, float* __restrict__ Ps)
{
    const int t = threadIdx.x, lane = t & 63, w = t >> 6;
    const int bh = blockIdx.x;           // b*4+h
    const int chunk = blockIdx.y;        // 0..NCHUNK-1
    const int b = bh >> 2, h = bh & 3;
    const int rows = NN / NCHUNK;        // 512
    const int per_wave = rows / 4;       // 128

    float m = -1e30f, s = 0.f;
    int n0 = chunk * rows + w * per_wave;
    for(int j = 0; j < per_wave; j++){
        int n = n0 + j;
        float v = b2f(attn[(size_t)(((size_t)b*NN + n)*HEAD + h)*RANK + lane]);
        if(v > m){ s = s * __expf(m - v) + 1.f; m = v; }
        else     { s += __expf(v - m); }
    }
    __shared__ float pm[4][64], ps[4][64];
    pm[w][lane] = m; ps[w][lane] = s;
    __syncthreads();
    if(t < 64){
        float M = pm[0][t], S = ps[0][t];
        #pragma unroll
        for(int i = 1; i < 4; i++){
            float m2 = pm[i][t], s2 = ps[i][t];
            float nm = fmaxf(M, m2);
            S = S * __expf(M - nm) + s2 * __expf(m2 - nm);
            M = nm;
        }
        Pm[(size_t)(bh*NCHUNK + chunk)*64 + t] = M;
        Ps[(size_t)(bh*NCHUNK + chunk)*64 + t] = S;
    }
}

// kC: combine chunk partials -> M,S per (b,h,r). grid 8 x 256.
__global__ void __launch_bounds__(256) kC(const float* __restrict__ Pm, const float* __restrict__ Ps,
                                          float* __restrict__ M, float* __restrict__ S)
{
    int o = blockIdx.x*256 + threadIdx.x;  // 0..2047 = (bh, r)
    int bh = o >> 6, r = o & 63;
    float m = -1e30f, s = 0.f;
    for(int c = 0; c < NCHUNK; c++){
        float m2 = Pm[(size_t)(bh*NCHUNK + c)*64 + r];
        float s2 = Ps[(size_t)(bh*NCHUNK + c)*64 + r];
        float nm = fmaxf(m, m2);
        s = s * __expf(m - nm) + s2 * __expf(m2 - nm);
        m = nm;
    }
    M[o] = m; S[o] = s;
}

// ---------------------------------------------------------------------------
// kD: pooled[b,r,h,d] += sum_n softmax_r(attn)[n,r] * xv[n,d]
// ---------------------------------------------------------------------------
__global__ void __launch_bounds__(256) kD(const bf16* __restrict__ attn, const float* __restrict__ xv,
                                          float* __restrict__ pooled)
{
    const int t = threadIdx.x, lane = t & 63, w = t >> 6;
    const int bh = blockIdx.x, chunk = blockIdx.y;
    const int b = bh >> 2, h = bh & 3;
    const int rows = NN / NCHUNK;      // 512
    const int iters = rows / 4;        // 128 per wave

    float acc[64];
    #pragma unroll
    for(int r = 0; r < 64; r++) acc[r] = 0.f;

    int n0 = chunk * rows;
    for(int j = 0; j < iters; j++){
        int n = n0 + w + 4*j;
        size_t base = (size_t)(((size_t)b*NN + n)*HEAD + h)*RANK;
        float L  = b2f(attn[base + lane]);
        float mx = wave_max64(L);
        float e  = __expf(L - mx);
        float ss = wave_sum64(e);
        float s1 = e / ss;
        float xvl = xv[base + lane];
        #pragma unroll
        for(int r = 0; r < 64; r++){
            float s1r = __shfl(s1, r, 64);
            acc[r] = fmaf(s1r, xvl, acc[r]);
        }
    }
    __shared__ float psum[64][64];  // [r][d] 16 KB
    if(w == 0){
        #pragma unroll
        for(int r = 0; r < 64; r++) psum[r][lane] = acc[r];
    }
    __syncthreads();
    for(int wv = 1; wv < 4; wv++){
        if(w == wv){
            #pragma unroll
            for(int r = 0; r < 64; r++) psum[r][lane] += acc[r];
        }
        __syncthreads();
    }
    #pragma unroll
    for(int i = 0; i < 16; i++){
        int flat = t + 256*i; int r = flat >> 6, d = flat & 63;
        atomicAdd(&pooled[(size_t)(((size_t)b*RANK + r)*HEAD + h)*HD + d], psum[r][d]);
    }
}

// ---------------------------------------------------------------------------
// kE: s2 = exp(attn - M)/S ; v = s2 @ pooled ; out = sig(alpha)*xv + sig(beta)*v
// xv lives in d_out (fp32); each thread reads xv[i] then overwrites out[i].
// ---------------------------------------------------------------------------
__global__ void __launch_bounds__(256) kE(const bf16* __restrict__ attn, const float* __restrict__ xvin,
                                          const float* __restrict__ pooled,
                                          const float* __restrict__ M, const float* __restrict__ S,
                                          const float* __restrict__ alpha, const float* __restrict__ beta,
                                          float* __restrict__ out)
{
    __shared__ float pooled_s[HEAD][RANK][HD];  // 64 KB, [h][r][d]
    __shared__ float M_s[HEAD][RANK], S_s[HEAD][RANK];

    const int t = threadIdx.x, lane = t & 63, w = t >> 6;
    const int bn0 = blockIdx.x * 16;
    const int b   = bn0 / NN;

    // stage pooled for this b (contiguous 16384 floats)
    {
        const float4* pb = (const float4*)(pooled + (size_t)b * 16384);
        #pragma unroll
        for(int ii = 0; ii < 16; ii++){
            int g = t + 256*ii;            // float4 index
            float4 p4 = pb[g];
            int j = g * 4;
            int r = j >> 8, h = (j >> 6) & 3, d = j & 63;
            *(float4*)&pooled_s[h][r][d] = p4;
        }
    }
    {
        int h = t >> 6, r = t & 63;
        M_s[h][r] = M[(b*HEAD + h)*64 + r];
        S_s[h][r] = S[(b*HEAD + h)*64 + r];
    }
    float sa[4], sb[4];
    #pragma unroll
    for(int h = 0; h < 4; h++){
        sa[h] = 1.f / (1.f + __expf(-alpha[h]));
        sb[h] = 1.f / (1.f + __expf(-beta[h]));
    }
    __syncthreads();

    for(int j = 0; j < 4; j++){
        int bn = bn0 + w + 4*j;
        #pragma unroll
        for(int h = 0; h < 4; h++){
            size_t base = (size_t)((size_t)bn*HEAD + h)*RANK;
            float L  = b2f(attn[base + lane]);
            float s2 = __expf(L - M_s[h][lane]) / S_s[h][lane];
            float xvl = xvin[base + lane];
            float v = 0.f;
            #pragma unroll
            for(int r = 0; r < 64; r++){
                float s2r = __shfl(s2, r, 64);
                v = fmaf(s2r, pooled_s[h][r][lane], v);
            }
            out[base + lane] = sa[h]*xvl + sb[h]*v;
        }
    }
}

extern "C" void kernel_launch(void* const* d_in, const int* in_sizes, int n_in,
                              void* d_out, int out_size, void* d_ws, size_t ws_size,
                              hipStream_t stream)
{
    (void)in_sizes; (void)n_in; (void)out_size; (void)ws_size;
    const float* x     = (const float*)d_in[0];
    const float* z     = (const float*)d_in[1];
    const float* Wq    = (const float*)d_in[2];
    const float* bq    = (const float*)d_in[3];
    const float* Km    = (const float*)d_in[4];
    const float* Wv    = (const float*)d_in[5];
    const float* bv    = (const float*)d_in[6];
    const float* alpha = (const float*)d_in[7];
    const float* beta  = (const float*)d_in[8];
    float* out = (float*)d_out;

    // xv (fp32) lives in d_out: kA writes it, kD reads it, kE reads element i
    // and overwrites out[i] in the same thread (no cross-thread hazard).
    float* xv = out;

    char* ws = (char*)d_ws;
    bf16*  attn   = (bf16*)(ws + 0);                 // 33,554,432 B
    float* pooled = (float*)(ws + 33554432);         // 524,288 B
    float* Mst    = (float*)(ws + 34078720);         // 8,192 B
    float* Sst    = (float*)(ws + 34086912);         // 8,192 B
    float* Pm     = (float*)(ws + 34095104);         // 131,072 B
    float* Ps     = (float*)(ws + 34226176);         // 131,072 B
                                                     // total: 34,357,248 B

    (void)hipMemsetAsync(pooled, 0, 524288, stream);
    kA<<<dim3(BN/16), 256, 0, stream>>>(x, z, Wq, bq, Km, Wv, bv, attn, xv);
    kB<<<dim3(32, NCHUNK), 256, 0, stream>>>(attn, Pm, Ps);
    kC<<<dim3(8), 256, 0, stream>>>(Pm, Ps, Mst, Sst);
    kD<<<dim3(32, NCHUNK), 256, 0, stream>>>(attn, xv, pooled);
    kE<<<dim3(BN/16), 256, 0, stream>>>(attn, xv, pooled, Mst, Sst, alpha, beta, out);
}

// Round 5
// 705.119 us; speedup vs baseline: 1.9159x; 1.9159x over previous
//
#include <hip/hip_runtime.h>
#include <hip/hip_bf16.h>

typedef __hip_bfloat16 bf16;

#define BB 8
#define NN 8192
#define DIM 256
#define HEAD 4
#define HD 64
#define RANK 64
#define BN (BB*NN)
#define NCHUNK 16   // n-chunks for kD partials (kC combines these)
#define ECHUNK 32   // n-chunks for kE

__device__ __forceinline__ float b2f(bf16 v){ return __bfloat162float(v); }
__device__ __forceinline__ bf16 f2b(float v){ return __float2bfloat16(v); }

__device__ __forceinline__ float wave_max64(float v){
    #pragma unroll
    for(int off = 32; off; off >>= 1) v = fmaxf(v, __shfl_xor(v, off, 64));
    return v;
}
__device__ __forceinline__ float wave_sum64(float v){
    #pragma unroll
    for(int off = 32; off; off >>= 1) v += __shfl_xor(v, off, 64);
    return v;
}

// ---------------------------------------------------------------------------
// kA: per 16-row block: q = z@Wq+bq ; attn[bn,h,r] = (q . K[r,h,:])/8 (bf16->ws);
//     xv = x@Wv+bv (fp32 -> d_out, reused as scratch).  (unchanged this round)
// ---------------------------------------------------------------------------
__global__ void __launch_bounds__(256) kA(
    const float* __restrict__ x, const float* __restrict__ z,
    const float* __restrict__ Wq, const float* __restrict__ bq,
    const float* __restrict__ Km, const float* __restrict__ Wv,
    const float* __restrict__ bv,
    bf16* __restrict__ attn, float* __restrict__ xv)
{
    __shared__ float buf[16][DIM];        // 16 KB: z rows, then x rows
    __shared__ float q_s[16][DIM];        // 16 KB
    __shared__ bf16  K_s[HEAD][HD][RANK]; // 32 KB, [h][d][r]

    const int t    = threadIdx.x;
    const int lane = t & 63;
    const int w    = t >> 6;
    const int bn0  = blockIdx.x * 16;
    const int c0   = lane * 4;   // output-column tile
    const int r0   = w * 4;      // row tile

    #pragma unroll 4
    for(int i = 0; i < 64; i++){
        int j = t + 256*i;           // 0..16383
        int r = j >> 8, h = (j >> 6) & 3, d = j & 63;
        K_s[h][d][r] = f2b(Km[j]);
    }
    {
        const float4* zr = (const float4*)(z + (size_t)bn0 * DIM);
        #pragma unroll
        for(int ii = 0; ii < 4; ii++){
            int g = t + 256*ii;
            int row = g >> 6, col = (g & 63) * 4;
            *(float4*)&buf[row][col] = zr[g];
        }
    }
    __syncthreads();

    float acc[4][4];
    // ---- GEMM q ----
    {
        const float4* Wq4 = (const float4*)Wq;
        const float4  bu  = ((const float4*)bq)[lane];
        #pragma unroll
        for(int ri = 0; ri < 4; ri++){ acc[ri][0]=bu.x; acc[ri][1]=bu.y; acc[ri][2]=bu.z; acc[ri][3]=bu.w; }
        for(int k = 0; k < DIM; k += 4){
            float wv[4][4];
            #pragma unroll
            for(int kk = 0; kk < 4; kk++){
                float4 u = Wq4[(size_t)(k+kk)*64 + lane];
                wv[kk][0]=u.x; wv[kk][1]=u.y; wv[kk][2]=u.z; wv[kk][3]=u.w;
            }
            #pragma unroll
            for(int ri = 0; ri < 4; ri++){
                float4 zv = *(const float4*)&buf[r0+ri][k];
                float zz[4] = {zv.x, zv.y, zv.z, zv.w};
                #pragma unroll
                for(int kk = 0; kk < 4; kk++){
                    #pragma unroll
                    for(int ci = 0; ci < 4; ci++)
                        acc[ri][ci] = fmaf(zz[kk], wv[kk][ci], acc[ri][ci]);
                }
            }
        }
        #pragma unroll
        for(int ri = 0; ri < 4; ri++)
            *(float4*)&q_s[r0+ri][c0] = make_float4(acc[ri][0],acc[ri][1],acc[ri][2],acc[ri][3]);
    }
    __syncthreads();

    {
        const float4* xr = (const float4*)(x + (size_t)bn0 * DIM);
        #pragma unroll
        for(int ii = 0; ii < 4; ii++){
            int g = t + 256*ii;
            int row = g >> 6, col = (g & 63) * 4;
            *(float4*)&buf[row][col] = xr[g];
        }
    }

    // ---- attn logits: wave w = head, lane = r ----
    {
        const int h = w;
        for(int i = 0; i < 16; i++){
            float a = 0.f;
            #pragma unroll
            for(int d = 0; d < HD; d += 4){
                float4 q4 = *(const float4*)&q_s[i][h*HD + d];
                a = fmaf(q4.x, b2f(K_s[h][d+0][lane]), a);
                a = fmaf(q4.y, b2f(K_s[h][d+1][lane]), a);
                a = fmaf(q4.z, b2f(K_s[h][d+2][lane]), a);
                a = fmaf(q4.w, b2f(K_s[h][d+3][lane]), a);
            }
            a *= 0.125f;
            attn[(size_t)((bn0+i)*HEAD + h)*RANK + lane] = f2b(a);
        }
    }
    __syncthreads();

    // ---- GEMM xv ----
    {
        const float4* Wv4 = (const float4*)Wv;
        const float4  bu  = ((const float4*)bv)[lane];
        #pragma unroll
        for(int ri = 0; ri < 4; ri++){ acc[ri][0]=bu.x; acc[ri][1]=bu.y; acc[ri][2]=bu.z; acc[ri][3]=bu.w; }
        for(int k = 0; k < DIM; k += 4){
            float wv[4][4];
            #pragma unroll
            for(int kk = 0; kk < 4; kk++){
                float4 u = Wv4[(size_t)(k+kk)*64 + lane];
                wv[kk][0]=u.x; wv[kk][1]=u.y; wv[kk][2]=u.z; wv[kk][3]=u.w;
            }
            #pragma unroll
            for(int ri = 0; ri < 4; ri++){
                float4 xvv = *(const float4*)&buf[r0+ri][k];
                float xx[4] = {xvv.x, xvv.y, xvv.z, xvv.w};
                #pragma unroll
                for(int kk = 0; kk < 4; kk++){
                    #pragma unroll
                    for(int ci = 0; ci < 4; ci++)
                        acc[ri][ci] = fmaf(xx[kk], wv[kk][ci], acc[ri][ci]);
                }
            }
        }
        #pragma unroll
        for(int ri = 0; ri < 4; ri++)
            ((float4*)xv)[(size_t)(bn0+r0+ri)*64 + lane] =
                make_float4(acc[ri][0],acc[ri][1],acc[ri][2],acc[ri][3]);
    }
}

// ---------------------------------------------------------------------------
// kD: per block (bh, chunk of 512 rows):
//   s1 = softmax_r(attn rows)  (wave shfl-reduce per row, 12 shfl)
//   pooled[b,:,h,:] += s1^T @ xv   (LDS-tiled register GEMM, 4x4 acc)
//   also accumulates per-column (r) online max/sum-exp over its rows -> Pm/Ps
// grid (32, NCHUNK). LDS ~37 KB.
// ---------------------------------------------------------------------------
__global__ void __launch_bounds__(256) kD(const bf16* __restrict__ attn, const float* __restrict__ xv,
                                          float* __restrict__ pooled,
                                          float* __restrict__ Pm, float* __restrict__ Ps)
{
    __shared__ float s1t[64][68];   // [row][r], pad 68 (16B-aligned rows)
    __shared__ float xvt[64][68];   // [row][d]
    __shared__ float pm[4][64], ps[4][64];

    const int t = threadIdx.x, lane = t & 63, w = t >> 6;
    const int bh = blockIdx.x, chunk = blockIdx.y;
    const int b = bh >> 2, h = bh & 3;
    const int rows = NN / NCHUNK;      // 512
    const int n0 = chunk * rows;
    const int tr = t >> 4, tc = t & 15;      // 16x16 thread grid
    const int r0 = tr * 4, d0 = tc * 4;

    float acc[4][4];
    #pragma unroll
    for(int ri = 0; ri < 4; ri++)
        #pragma unroll
        for(int ci = 0; ci < 4; ci++) acc[ri][ci] = 0.f;

    float mc = -1e30f, sc = 0.f;    // per-(wave,lane=r) column stats

    for(int st = 0; st < rows/64; st++){
        int nst = n0 + st*64;
        // stage xv rows [nst..nst+63] head h -> xvt
        {
            #pragma unroll
            for(int ii = 0; ii < 4; ii++){
                int g = t + 256*ii;            // 0..1023 float4s
                int row = g >> 4, c4 = g & 15;
                float4 v = ((const float4*)xv)[(size_t)(b*NN + nst + row)*64 + h*16 + c4];
                *(float4*)&xvt[row][c4*4] = v;
            }
        }
        // softmax over r per row; wave w handles rows w*16..w*16+15
        #pragma unroll 1
        for(int i = 0; i < 16; i++){
            int lrow = w*16 + i;
            int n = nst + lrow;
            float L = b2f(attn[(size_t)(((size_t)b*NN + n)*HEAD + h)*RANK + lane]);
            float mx = wave_max64(L);
            float e  = __expf(L - mx);
            float ss = wave_sum64(e);
            s1t[lrow][lane] = e / ss;
            // column online stats (raw L), lane = r
            float nm = fmaxf(mc, L);
            sc = sc * __expf(mc - nm) + __expf(L - nm);
            mc = nm;
        }
        __syncthreads();
        // GEMM: acc[r0+ri][d0+ci] += sum_row s1t[row][r] * xvt[row][d]
        for(int k = 0; k < 64; k += 4){
            #pragma unroll
            for(int kk = 0; kk < 4; kk++){
                float4 a4 = *(const float4*)&s1t[k+kk][r0];
                float4 b4 = *(const float4*)&xvt[k+kk][d0];
                float aa[4] = {a4.x,a4.y,a4.z,a4.w};
                float bb[4] = {b4.x,b4.y,b4.z,b4.w};
                #pragma unroll
                for(int ri = 0; ri < 4; ri++)
                    #pragma unroll
                    for(int ci = 0; ci < 4; ci++)
                        acc[ri][ci] = fmaf(aa[ri], bb[ci], acc[ri][ci]);
            }
        }
        __syncthreads();
    }

    // write pooled partial (atomic)
    #pragma unroll
    for(int ri = 0; ri < 4; ri++)
        #pragma unroll
        for(int ci = 0; ci < 4; ci++)
            atomicAdd(&pooled[(size_t)(((size_t)b*RANK + r0+ri)*HEAD + h)*HD + d0+ci], acc[ri][ci]);

    // combine column stats across waves -> Pm/Ps
    pm[w][lane] = mc; ps[w][lane] = sc;
    __syncthreads();
    if(t < 64){
        float M = pm[0][t], S = ps[0][t];
        #pragma unroll
        for(int i = 1; i < 4; i++){
            float m2 = pm[i][t], s2 = ps[i][t];
            float nm = fmaxf(M, m2);
            S = S * __expf(M - nm) + s2 * __expf(m2 - nm);
            M = nm;
        }
        Pm[(size_t)(bh*NCHUNK + chunk)*64 + t] = M;
        Ps[(size_t)(bh*NCHUNK + chunk)*64 + t] = S;
    }
}

// kC: combine chunk partials -> M,S per (b,h,r). grid 8 x 256.
__global__ void __launch_bounds__(256) kC(const float* __restrict__ Pm, const float* __restrict__ Ps,
                                          float* __restrict__ M, float* __restrict__ S)
{
    int o = blockIdx.x*256 + threadIdx.x;  // 0..2047 = (bh, r)
    int bh = o >> 6, r = o & 63;
    float m = -1e30f, s = 0.f;
    for(int c = 0; c < NCHUNK; c++){
        float m2 = Pm[(size_t)(bh*NCHUNK + c)*64 + r];
        float s2 = Ps[(size_t)(bh*NCHUNK + c)*64 + r];
        float nm = fmaxf(m, m2);
        s = s * __expf(m - nm) + s2 * __expf(m2 - nm);
        m = nm;
    }
    M[o] = m; S[o] = s;
}

// ---------------------------------------------------------------------------
// kE: per block (bh, chunk of 256 rows): stage pooled[b,:,h,:] (16 KB);
//   per 64-row sub-tile: s2 = exp(attn - M)/S (no shfl), then
//   v = s2 @ pooled (LDS-tiled register GEMM), out = sa*xv + sb*v.
// grid (32, ECHUNK). LDS ~35 KB.
// ---------------------------------------------------------------------------
__global__ void __launch_bounds__(256) kE(const bf16* __restrict__ attn, const float* __restrict__ xvin,
                                          const float* __restrict__ pooled,
                                          const float* __restrict__ M, const float* __restrict__ S,
                                          const float* __restrict__ alpha, const float* __restrict__ beta,
                                          float* __restrict__ out)
{
    __shared__ float pooled_s[64][68];  // [r][d]
    __shared__ float s2t[64][68];       // [row][r]

    const int t = threadIdx.x, lane = t & 63, w = t >> 6;
    const int bh = blockIdx.x, chunk = blockIdx.y;
    const int b = bh >> 2, h = bh & 3;
    const int rows = NN / ECHUNK;      // 256
    const int n0 = chunk * rows;
    const int tr = t >> 4, tc = t & 15;
    const int row0 = tr * 4, d0 = tc * 4;

    // stage pooled[b,:,h,:]
    {
        #pragma unroll
        for(int ii = 0; ii < 4; ii++){
            int g = t + 256*ii;            // 0..1023 float4s
            int r = g >> 4, c4 = g & 15;
            float4 v = ((const float4*)pooled)[(size_t)((b*RANK + r)*HEAD + h)*16 + c4];
            *(float4*)&pooled_s[r][c4*4] = v;
        }
    }
    const float Mv   = M[bh*64 + lane];
    const float invS = 1.f / S[bh*64 + lane];
    const float sa = 1.f / (1.f + __expf(-alpha[h]));
    const float sb = 1.f / (1.f + __expf(-beta[h]));
    __syncthreads();

    for(int st = 0; st < rows/64; st++){
        int nst = n0 + st*64;
        // s2 rows; wave w handles rows w*16..w*16+15 (no shfl needed)
        #pragma unroll 1
        for(int i = 0; i < 16; i++){
            int lrow = w*16 + i;
            int n = nst + lrow;
            float L = b2f(attn[(size_t)(((size_t)b*NN + n)*HEAD + h)*RANK + lane]);
            s2t[lrow][lane] = __expf(L - Mv) * invS;
        }
        __syncthreads();
        // GEMM: v[row][d] = sum_r s2t[row][r] * pooled_s[r][d]
        float acc[4][4];
        #pragma unroll
        for(int ri = 0; ri < 4; ri++)
            #pragma unroll
            for(int ci = 0; ci < 4; ci++) acc[ri][ci] = 0.f;
        for(int k = 0; k < 64; k += 4){
            float4 a4[4];
            #pragma unroll
            for(int ri = 0; ri < 4; ri++) a4[ri] = *(const float4*)&s2t[row0+ri][k];
            #pragma unroll
            for(int kk = 0; kk < 4; kk++){
                float4 b4 = *(const float4*)&pooled_s[k+kk][d0];
                float bb[4] = {b4.x,b4.y,b4.z,b4.w};
                #pragma unroll
                for(int ri = 0; ri < 4; ri++){
                    float av = (kk==0)?a4[ri].x:(kk==1)?a4[ri].y:(kk==2)?a4[ri].z:a4[ri].w;
                    #pragma unroll
                    for(int ci = 0; ci < 4; ci++)
                        acc[ri][ci] = fmaf(av, bb[ci], acc[ri][ci]);
                }
            }
        }
        // epilogue: out = sa*xv + sb*v   (same-thread read->write on d_out)
        #pragma unroll
        for(int ri = 0; ri < 4; ri++){
            int n = nst + row0 + ri;
            size_t g4 = (size_t)(b*NN + n)*64 + h*16 + tc;
            float4 xv4 = ((const float4*)xvin)[g4];
            float4 o4;
            o4.x = sa*xv4.x + sb*acc[ri][0];
            o4.y = sa*xv4.y + sb*acc[ri][1];
            o4.z = sa*xv4.z + sb*acc[ri][2];
            o4.w = sa*xv4.w + sb*acc[ri][3];
            ((float4*)out)[g4] = o4;
        }
        __syncthreads();
    }
}

extern "C" void kernel_launch(void* const* d_in, const int* in_sizes, int n_in,
                              void* d_out, int out_size, void* d_ws, size_t ws_size,
                              hipStream_t stream)
{
    (void)in_sizes; (void)n_in; (void)out_size; (void)ws_size;
    const float* x     = (const float*)d_in[0];
    const float* z     = (const float*)d_in[1];
    const float* Wq    = (const float*)d_in[2];
    const float* bq    = (const float*)d_in[3];
    const float* Km    = (const float*)d_in[4];
    const float* Wv    = (const float*)d_in[5];
    const float* bv    = (const float*)d_in[6];
    const float* alpha = (const float*)d_in[7];
    const float* beta  = (const float*)d_in[8];
    float* out = (float*)d_out;

    // xv (fp32) lives in d_out: kA writes it, kD reads it, kE reads element i
    // and overwrites out[i] in the same thread (no cross-thread hazard).
    float* xv = out;

    char* ws = (char*)d_ws;
    bf16*  attn   = (bf16*)(ws + 0);                 // 33,554,432 B
    float* pooled = (float*)(ws + 33554432);         // 524,288 B
    float* Mst    = (float*)(ws + 34078720);         // 8,192 B
    float* Sst    = (float*)(ws + 34086912);         // 8,192 B
    float* Pm     = (float*)(ws + 34095104);         // 131,072 B
    float* Ps     = (float*)(ws + 34226176);         // 131,072 B
                                                     // total: 34,357,248 B

    (void)hipMemsetAsync(pooled, 0, 524288, stream);
    kA<<<dim3(BN/16), 256, 0, stream>>>(x, z, Wq, bq, Km, Wv, bv, attn, xv);
    kD<<<dim3(32, NCHUNK), 256, 0, stream>>>(attn, xv, pooled, Pm, Ps);
    kC<<<dim3(8), 256, 0, stream>>>(Pm, Ps, Mst, Sst);
    kE<<<dim3(32, ECHUNK), 256, 0, stream>>>(attn, xv, pooled, Mst, Sst, alpha, beta, out);
}

// Round 6
// 447.681 us; speedup vs baseline: 3.0177x; 1.5750x over previous
//
#include <hip/hip_runtime.h>
#include <hip/hip_bf16.h>

typedef __hip_bfloat16 bf16;
typedef __attribute__((ext_vector_type(8))) __bf16 bf16x8;
typedef __attribute__((ext_vector_type(4))) float f32x4;

#define BB 8
#define NN 8192
#define DIM 256
#define HEAD 4
#define HD 64
#define RANK 64
#define BN (BB*NN)
#define NCHUNK 16   // n-chunks for kD partials (kC combines these)
#define ECHUNK 32   // n-chunks for kE

__device__ __forceinline__ float b2f(bf16 v){ return __bfloat162float(v); }
__device__ __forceinline__ bf16 f2b(float v){ return __float2bfloat16(v); }
__device__ __forceinline__ __bf16 f2bb(float f){
    bf16 h = __float2bfloat16(f);
    return *reinterpret_cast<__bf16*>(&h);
}

__device__ __forceinline__ float wave_max64(float v){
    #pragma unroll
    for(int off = 32; off; off >>= 1) v = fmaxf(v, __shfl_xor(v, off, 64));
    return v;
}
__device__ __forceinline__ float wave_sum64(float v){
    #pragma unroll
    for(int off = 32; off; off >>= 1) v += __shfl_xor(v, off, 64);
    return v;
}

// ---------------------------------------------------------------------------
// kW: precompute (tiny)
//   WattnT[c][f] = bf16( 0.125 * sum_d Wq[f, h*64+d] * K[r,h,d] ),  c = h*64+r
//   WvT[c][f]    = bf16( Wv[f][c] )
//   battn[c]     = 0.125 * sum_d bq[h*64+d] * K[r,h,d]
// grid 256 blocks x 256 threads (t = f).
// ---------------------------------------------------------------------------
__global__ void __launch_bounds__(256) kW(
    const float* __restrict__ Wq, const float* __restrict__ bq,
    const float* __restrict__ Km, const float* __restrict__ Wv,
    unsigned short* __restrict__ WattnT, unsigned short* __restrict__ WvT,
    float* __restrict__ battn)
{
    const int c = blockIdx.x;       // output col = h*64+r
    const int h = c >> 6, r = c & 63;
    const int t = threadIdx.x;      // f
    __shared__ float Ks[64];
    if(t < 64) Ks[t] = Km[((size_t)r*HEAD + h)*64 + t];
    __syncthreads();

    const float* wqrow = Wq + (size_t)t*DIM + h*64;
    float a = 0.f;
    #pragma unroll
    for(int d = 0; d < 64; d++) a = fmaf(wqrow[d], Ks[d], a);
    bf16 hb = f2b(0.125f * a);
    WattnT[(size_t)c*DIM + t] = *(unsigned short*)&hb;
    bf16 hv = f2b(Wv[(size_t)t*DIM + c]);
    WvT[(size_t)c*DIM + t] = *(unsigned short*)&hv;
    if(t == 0){
        float bb = 0.f;
        for(int d = 0; d < 64; d++) bb += bq[h*64+d]*Ks[d];
        battn[c] = 0.125f * bb;
    }
}

// ---------------------------------------------------------------------------
// kA2: MFMA GEMM  OUT[64 x 256] = A[64 x 256] @ W^T + bias, per block.
//   A fp32 (x or z), W staged from WT ([n][k] bf16). 4 waves, each owns a
//   64x64 tile via 4x4 of mfma_f32_16x16x32_bf16. bf16out selects epilogue.
// grid BN/64 blocks x 256 threads. LDS ~25.6 KB.
// ---------------------------------------------------------------------------
__global__ void __launch_bounds__(256) kA2(
    const float* __restrict__ A, const unsigned short* __restrict__ WT,
    const float* __restrict__ bias,
    float* __restrict__ outF, bf16* __restrict__ outB, const int bf16out)
{
    __shared__ __attribute__((aligned(16))) __bf16 As[64][40];   // rows x k-slab (pad 40)
    __shared__ __attribute__((aligned(16))) __bf16 Ws[256][40];  // cols(n) x k-slab

    const int t    = threadIdx.x;
    const int lane = t & 63;
    const int w    = t >> 6;
    const int q    = lane >> 4;    // quad
    const int l15  = lane & 15;
    const int brow = blockIdx.x * 64;

    f32x4 acc[4][4];
    #pragma unroll
    for(int tm = 0; tm < 4; tm++)
        #pragma unroll
        for(int tn = 0; tn < 4; tn++) acc[tm][tn] = (f32x4){0.f,0.f,0.f,0.f};

    const int arow = t >> 2, aseg = t & 3;      // A staging map

    for(int k0 = 0; k0 < DIM; k0 += 32){
        // stage A slab: 64 rows x 32 k (fp32 -> bf16)
        {
            const float* ap = A + (size_t)(brow + arow)*DIM + k0 + aseg*8;
            float4 v0 = *(const float4*)(ap + 0);
            float4 v1 = *(const float4*)(ap + 4);
            __attribute__((aligned(16))) __bf16 tmp[8] = {
                f2bb(v0.x), f2bb(v0.y), f2bb(v0.z), f2bb(v0.w),
                f2bb(v1.x), f2bb(v1.y), f2bb(v1.z), f2bb(v1.w)};
            *(bf16x8*)&As[arow][aseg*8] = *(bf16x8*)tmp;
        }
        // stage W slab: 256 n-rows x 32 k (bf16 16B copies)
        #pragma unroll
        for(int ii = 0; ii < 4; ii++){
            int c = t + 256*ii;                 // 0..1023 16B-chunks
            int n = c >> 2, seg = c & 3;
            uint4 wv = *(const uint4*)(WT + (size_t)n*DIM + k0 + seg*8);
            *(uint4*)&Ws[n][seg*8] = wv;
        }
        __syncthreads();

        bf16x8 af[4], bf[4];
        #pragma unroll
        for(int tm = 0; tm < 4; tm++) af[tm] = *(const bf16x8*)&As[tm*16 + l15][q*8];
        #pragma unroll
        for(int tn = 0; tn < 4; tn++) bf[tn] = *(const bf16x8*)&Ws[w*64 + tn*16 + l15][q*8];
        #pragma unroll
        for(int tm = 0; tm < 4; tm++)
            #pragma unroll
            for(int tn = 0; tn < 4; tn++)
                acc[tm][tn] = __builtin_amdgcn_mfma_f32_16x16x32_bf16(
                    af[tm], bf[tn], acc[tm][tn], 0, 0, 0);
        __syncthreads();
    }

    // epilogue: D[row=(q*4+reg), col=l15] within each 16x16 tile
    #pragma unroll
    for(int tn = 0; tn < 4; tn++){
        int col = w*64 + tn*16 + l15;
        float bcol = bias[col];
        #pragma unroll
        for(int tm = 0; tm < 4; tm++){
            #pragma unroll
            for(int reg = 0; reg < 4; reg++){
                int grow = brow + tm*16 + q*4 + reg;
                float v = acc[tm][tn][reg] + bcol;
                if(bf16out) outB[(size_t)grow*256 + col] = f2b(v);
                else        outF[(size_t)grow*256 + col] = v;
            }
        }
    }
}

// ---------------------------------------------------------------------------
// kD: per block (bh, chunk of 512 rows):
//   s1 = softmax_r(attn rows); pooled[b,:,h,:] += s1^T @ xv (4x4 reg GEMM);
//   per-column online max/sum-exp -> Pm/Ps.
// ---------------------------------------------------------------------------
__global__ void __launch_bounds__(256) kD(const bf16* __restrict__ attn, const float* __restrict__ xv,
                                          float* __restrict__ pooled,
                                          float* __restrict__ Pm, float* __restrict__ Ps)
{
    __shared__ float s1t[64][68];   // [row][r]
    __shared__ float xvt[64][68];   // [row][d]
    __shared__ float pm[4][64], ps[4][64];

    const int t = threadIdx.x, lane = t & 63, w = t >> 6;
    const int bh = blockIdx.x, chunk = blockIdx.y;
    const int b = bh >> 2, h = bh & 3;
    const int rows = NN / NCHUNK;      // 512
    const int n0 = chunk * rows;
    const int tr = t >> 4, tc = t & 15;
    const int r0 = tr * 4, d0 = tc * 4;

    float acc[4][4];
    #pragma unroll
    for(int ri = 0; ri < 4; ri++)
        #pragma unroll
        for(int ci = 0; ci < 4; ci++) acc[ri][ci] = 0.f;

    float mc = -1e30f, sc = 0.f;

    for(int st = 0; st < rows/64; st++){
        int nst = n0 + st*64;
        {
            #pragma unroll
            for(int ii = 0; ii < 4; ii++){
                int g = t + 256*ii;
                int row = g >> 4, c4 = g & 15;
                float4 v = ((const float4*)xv)[(size_t)(b*NN + nst + row)*64 + h*16 + c4];
                *(float4*)&xvt[row][c4*4] = v;
            }
        }
        #pragma unroll 1
        for(int i = 0; i < 16; i++){
            int lrow = w*16 + i;
            int n = nst + lrow;
            float L = b2f(attn[(size_t)(((size_t)b*NN + n)*HEAD + h)*RANK + lane]);
            float mx = wave_max64(L);
            float e  = __expf(L - mx);
            float ss = wave_sum64(e);
            s1t[lrow][lane] = e / ss;
            float nm = fmaxf(mc, L);
            sc = sc * __expf(mc - nm) + __expf(L - nm);
            mc = nm;
        }
        __syncthreads();
        for(int k = 0; k < 64; k += 4){
            #pragma unroll
            for(int kk = 0; kk < 4; kk++){
                float4 a4 = *(const float4*)&s1t[k+kk][r0];
                float4 b4 = *(const float4*)&xvt[k+kk][d0];
                float aa[4] = {a4.x,a4.y,a4.z,a4.w};
                float bb[4] = {b4.x,b4.y,b4.z,b4.w};
                #pragma unroll
                for(int ri = 0; ri < 4; ri++)
                    #pragma unroll
                    for(int ci = 0; ci < 4; ci++)
                        acc[ri][ci] = fmaf(aa[ri], bb[ci], acc[ri][ci]);
            }
        }
        __syncthreads();
    }

    #pragma unroll
    for(int ri = 0; ri < 4; ri++)
        #pragma unroll
        for(int ci = 0; ci < 4; ci++)
            atomicAdd(&pooled[(size_t)(((size_t)b*RANK + r0+ri)*HEAD + h)*HD + d0+ci], acc[ri][ci]);

    pm[w][lane] = mc; ps[w][lane] = sc;
    __syncthreads();
    if(t < 64){
        float M = pm[0][t], S = ps[0][t];
        #pragma unroll
        for(int i = 1; i < 4; i++){
            float m2 = pm[i][t], s2 = ps[i][t];
            float nm = fmaxf(M, m2);
            S = S * __expf(M - nm) + s2 * __expf(m2 - nm);
            M = nm;
        }
        Pm[(size_t)(bh*NCHUNK + chunk)*64 + t] = M;
        Ps[(size_t)(bh*NCHUNK + chunk)*64 + t] = S;
    }
}

// kC: combine chunk partials -> M,S per (b,h,r). grid 8 x 256.
__global__ void __launch_bounds__(256) kC(const float* __restrict__ Pm, const float* __restrict__ Ps,
                                          float* __restrict__ M, float* __restrict__ S)
{
    int o = blockIdx.x*256 + threadIdx.x;
    int bh = o >> 6, r = o & 63;
    float m = -1e30f, s = 0.f;
    for(int c = 0; c < NCHUNK; c++){
        float m2 = Pm[(size_t)(bh*NCHUNK + c)*64 + r];
        float s2 = Ps[(size_t)(bh*NCHUNK + c)*64 + r];
        float nm = fmaxf(m, m2);
        s = s * __expf(m - nm) + s2 * __expf(m2 - nm);
        m = nm;
    }
    M[o] = m; S[o] = s;
}

// ---------------------------------------------------------------------------
// kE: per block (bh, chunk of 256 rows): stage pooled[b,:,h,:];
//   s2 = exp(attn - M)/S; v = s2 @ pooled; out = sa*xv + sb*v.
// ---------------------------------------------------------------------------
__global__ void __launch_bounds__(256) kE(const bf16* __restrict__ attn, const float* __restrict__ xvin,
                                          const float* __restrict__ pooled,
                                          const float* __restrict__ M, const float* __restrict__ S,
                                          const float* __restrict__ alpha, const float* __restrict__ beta,
                                          float* __restrict__ out)
{
    __shared__ float pooled_s[64][68];  // [r][d]
    __shared__ float s2t[64][68];       // [row][r]

    const int t = threadIdx.x, lane = t & 63, w = t >> 6;
    const int bh = blockIdx.x, chunk = blockIdx.y;
    const int b = bh >> 2, h = bh & 3;
    const int rows = NN / ECHUNK;      // 256
    const int n0 = chunk * rows;
    const int tr = t >> 4, tc = t & 15;
    const int row0 = tr * 4, d0 = tc * 4;

    {
        #pragma unroll
        for(int ii = 0; ii < 4; ii++){
            int g = t + 256*ii;
            int r = g >> 4, c4 = g & 15;
            float4 v = ((const float4*)pooled)[(size_t)((b*RANK + r)*HEAD + h)*16 + c4];
            *(float4*)&pooled_s[r][c4*4] = v;
        }
    }
    const float Mv   = M[bh*64 + lane];
    const float invS = 1.f / S[bh*64 + lane];
    const float sa = 1.f / (1.f + __expf(-alpha[h]));
    const float sb = 1.f / (1.f + __expf(-beta[h]));
    __syncthreads();

    for(int st = 0; st < rows/64; st++){
        int nst = n0 + st*64;
        #pragma unroll 1
        for(int i = 0; i < 16; i++){
            int lrow = w*16 + i;
            int n = nst + lrow;
            float L = b2f(attn[(size_t)(((size_t)b*NN + n)*HEAD + h)*RANK + lane]);
            s2t[lrow][lane] = __expf(L - Mv) * invS;
        }
        __syncthreads();
        float acc[4][4];
        #pragma unroll
        for(int ri = 0; ri < 4; ri++)
            #pragma unroll
            for(int ci = 0; ci < 4; ci++) acc[ri][ci] = 0.f;
        for(int k = 0; k < 64; k += 4){
            float4 a4[4];
            #pragma unroll
            for(int ri = 0; ri < 4; ri++) a4[ri] = *(const float4*)&s2t[row0+ri][k];
            #pragma unroll
            for(int kk = 0; kk < 4; kk++){
                float4 b4 = *(const float4*)&pooled_s[k+kk][d0];
                float bb[4] = {b4.x,b4.y,b4.z,b4.w};
                #pragma unroll
                for(int ri = 0; ri < 4; ri++){
                    float av = (kk==0)?a4[ri].x:(kk==1)?a4[ri].y:(kk==2)?a4[ri].z:a4[ri].w;
                    #pragma unroll
                    for(int ci = 0; ci < 4; ci++)
                        acc[ri][ci] = fmaf(av, bb[ci], acc[ri][ci]);
                }
            }
        }
        #pragma unroll
        for(int ri = 0; ri < 4; ri++){
            int n = nst + row0 + ri;
            size_t g4 = (size_t)(b*NN + n)*64 + h*16 + tc;
            float4 xv4 = ((const float4*)xvin)[g4];
            float4 o4;
            o4.x = sa*xv4.x + sb*acc[ri][0];
            o4.y = sa*xv4.y + sb*acc[ri][1];
            o4.z = sa*xv4.z + sb*acc[ri][2];
            o4.w = sa*xv4.w + sb*acc[ri][3];
            ((float4*)out)[g4] = o4;
        }
        __syncthreads();
    }
}

extern "C" void kernel_launch(void* const* d_in, const int* in_sizes, int n_in,
                              void* d_out, int out_size, void* d_ws, size_t ws_size,
                              hipStream_t stream)
{
    (void)in_sizes; (void)n_in; (void)out_size; (void)ws_size;
    const float* x     = (const float*)d_in[0];
    const float* z     = (const float*)d_in[1];
    const float* Wq    = (const float*)d_in[2];
    const float* bq    = (const float*)d_in[3];
    const float* Km    = (const float*)d_in[4];
    const float* Wv    = (const float*)d_in[5];
    const float* bv    = (const float*)d_in[6];
    const float* alpha = (const float*)d_in[7];
    const float* beta  = (const float*)d_in[8];
    float* out = (float*)d_out;

    // xv (fp32) lives in d_out: kA2 writes it, kD reads it, kE reads element i
    // and overwrites out[i] in the same thread (no cross-thread hazard).
    float* xv = out;

    char* ws = (char*)d_ws;
    bf16*  attn   = (bf16*)(ws + 0);                          // 33,554,432 B
    float* pooled = (float*)(ws + 33554432);                  // 524,288 B
    float* Mst    = (float*)(ws + 34078720);                  // 8,192 B
    float* Sst    = (float*)(ws + 34086912);                  // 8,192 B
    float* Pm     = (float*)(ws + 34095104);                  // 131,072 B
    float* Ps     = (float*)(ws + 34226176);                  // 131,072 B
    unsigned short* WattnT = (unsigned short*)(ws + 34357248); // 131,072 B
    unsigned short* WvT    = (unsigned short*)(ws + 34488320); // 131,072 B
    float* battn  = (float*)(ws + 34619392);                  // 1,024 B
                                                              // total: 34,620,416 B

    (void)hipMemsetAsync(pooled, 0, 524288, stream);
    kW<<<dim3(256), 256, 0, stream>>>(Wq, bq, Km, Wv, WattnT, WvT, battn);
    // xv = x @ Wv + bv   (fp32 -> d_out)
    kA2<<<dim3(BN/64), 256, 0, stream>>>(x, WvT, bv, xv, nullptr, 0);
    // attn = z @ Wattn + battn  (bf16 -> ws; 0.125 folded into weights)
    kA2<<<dim3(BN/64), 256, 0, stream>>>(z, WattnT, battn, nullptr, attn, 1);
    kD<<<dim3(32, NCHUNK), 256, 0, stream>>>(attn, xv, pooled, Pm, Ps);
    kC<<<dim3(8), 256, 0, stream>>>(Pm, Ps, Mst, Sst);
    kE<<<dim3(32, ECHUNK), 256, 0, stream>>>(attn, xv, pooled, Mst, Sst, alpha, beta, out);
}

// Round 7
// 398.123 us; speedup vs baseline: 3.3933x; 1.1245x over previous
//
#include <hip/hip_runtime.h>
#include <hip/hip_bf16.h>

typedef __hip_bfloat16 bf16;
typedef __attribute__((ext_vector_type(8))) __bf16 bf16x8;
typedef __attribute__((ext_vector_type(4))) float f32x4;

#define BB 8
#define NN 8192
#define DIM 256
#define HEAD 4
#define HD 64
#define RANK 64
#define BN (BB*NN)
#define NCHUNK 32   // n-chunks for kD partials (kC combines these)
#define ECHUNK 64   // n-chunks for kE

__device__ __forceinline__ float b2f(bf16 v){ return __bfloat162float(v); }
__device__ __forceinline__ bf16 f2b(float v){ return __float2bfloat16(v); }
__device__ __forceinline__ __bf16 f2bb(float f){
    bf16 h = __float2bfloat16(f);
    return *reinterpret_cast<__bf16*>(&h);
}

__device__ __forceinline__ float wave_max64(float v){
    #pragma unroll
    for(int off = 32; off; off >>= 1) v = fmaxf(v, __shfl_xor(v, off, 64));
    return v;
}
__device__ __forceinline__ float wave_sum64(float v){
    #pragma unroll
    for(int off = 32; off; off >>= 1) v += __shfl_xor(v, off, 64);
    return v;
}

// ---------------------------------------------------------------------------
// kW: precompute (tiny)
//   WattnT[c][f] = bf16( 0.125 * sum_d Wq[f, h*64+d] * K[r,h,d] ),  c = h*64+r
//   WvT[c][f]    = bf16( Wv[f][c] )
//   battn[c]     = 0.125 * sum_d bq[h*64+d] * K[r,h,d]
// ---------------------------------------------------------------------------
__global__ void __launch_bounds__(256) kW(
    const float* __restrict__ Wq, const float* __restrict__ bq,
    const float* __restrict__ Km, const float* __restrict__ Wv,
    unsigned short* __restrict__ WattnT, unsigned short* __restrict__ WvT,
    float* __restrict__ battn)
{
    const int c = blockIdx.x;       // output col = h*64+r
    const int h = c >> 6, r = c & 63;
    const int t = threadIdx.x;      // f
    __shared__ float Ks[64];
    if(t < 64) Ks[t] = Km[((size_t)r*HEAD + h)*64 + t];
    __syncthreads();

    const float* wqrow = Wq + (size_t)t*DIM + h*64;
    float a = 0.f;
    #pragma unroll
    for(int d = 0; d < 64; d++) a = fmaf(wqrow[d], Ks[d], a);
    bf16 hb = f2b(0.125f * a);
    WattnT[(size_t)c*DIM + t] = *(unsigned short*)&hb;
    bf16 hv = f2b(Wv[(size_t)t*DIM + c]);
    WvT[(size_t)c*DIM + t] = *(unsigned short*)&hv;
    if(t == 0){
        float bb = 0.f;
        for(int d = 0; d < 64; d++) bb += bq[h*64+d]*Ks[d];
        battn[c] = 0.125f * bb;
    }
}

// ---------------------------------------------------------------------------
// kA2: MFMA GEMM  OUT[64 x 256] = A[64 x 256] @ W^T + bias, per block.
// ---------------------------------------------------------------------------
__global__ void __launch_bounds__(256) kA2(
    const float* __restrict__ A, const unsigned short* __restrict__ WT,
    const float* __restrict__ bias,
    float* __restrict__ outF, bf16* __restrict__ outB, const int bf16out)
{
    __shared__ __attribute__((aligned(16))) __bf16 As[64][40];   // rows x k-slab (pad 40)
    __shared__ __attribute__((aligned(16))) __bf16 Ws[256][40];  // cols(n) x k-slab

    const int t    = threadIdx.x;
    const int lane = t & 63;
    const int w    = t >> 6;
    const int q    = lane >> 4;    // quad
    const int l15  = lane & 15;
    const int brow = blockIdx.x * 64;

    f32x4 acc[4][4];
    #pragma unroll
    for(int tm = 0; tm < 4; tm++)
        #pragma unroll
        for(int tn = 0; tn < 4; tn++) acc[tm][tn] = (f32x4){0.f,0.f,0.f,0.f};

    const int arow = t >> 2, aseg = t & 3;

    for(int k0 = 0; k0 < DIM; k0 += 32){
        {
            const float* ap = A + (size_t)(brow + arow)*DIM + k0 + aseg*8;
            float4 v0 = *(const float4*)(ap + 0);
            float4 v1 = *(const float4*)(ap + 4);
            __attribute__((aligned(16))) __bf16 tmp[8] = {
                f2bb(v0.x), f2bb(v0.y), f2bb(v0.z), f2bb(v0.w),
                f2bb(v1.x), f2bb(v1.y), f2bb(v1.z), f2bb(v1.w)};
            *(bf16x8*)&As[arow][aseg*8] = *(bf16x8*)tmp;
        }
        #pragma unroll
        for(int ii = 0; ii < 4; ii++){
            int c = t + 256*ii;
            int n = c >> 2, seg = c & 3;
            uint4 wv = *(const uint4*)(WT + (size_t)n*DIM + k0 + seg*8);
            *(uint4*)&Ws[n][seg*8] = wv;
        }
        __syncthreads();

        bf16x8 af[4], bf[4];
        #pragma unroll
        for(int tm = 0; tm < 4; tm++) af[tm] = *(const bf16x8*)&As[tm*16 + l15][q*8];
        #pragma unroll
        for(int tn = 0; tn < 4; tn++) bf[tn] = *(const bf16x8*)&Ws[w*64 + tn*16 + l15][q*8];
        #pragma unroll
        for(int tm = 0; tm < 4; tm++)
            #pragma unroll
            for(int tn = 0; tn < 4; tn++)
                acc[tm][tn] = __builtin_amdgcn_mfma_f32_16x16x32_bf16(
                    af[tm], bf[tn], acc[tm][tn], 0, 0, 0);
        __syncthreads();
    }

    #pragma unroll
    for(int tn = 0; tn < 4; tn++){
        int col = w*64 + tn*16 + l15;
        float bcol = bias[col];
        #pragma unroll
        for(int tm = 0; tm < 4; tm++){
            #pragma unroll
            for(int reg = 0; reg < 4; reg++){
                int grow = brow + tm*16 + q*4 + reg;
                float v = acc[tm][tn][reg] + bcol;
                if(bf16out) outB[(size_t)grow*256 + col] = f2b(v);
                else        outF[(size_t)grow*256 + col] = v;
            }
        }
    }
}

// ---------------------------------------------------------------------------
// kD: per block (bh, chunk of 256 rows):
//   s1 = softmax_r(attn rows); pooled[b,:,h,:] += s1^T @ xv (4x4 reg GEMM);
//   per-column online max/sum-exp -> Pm/Ps (batched merge, no serial chain).
// grid (32, NCHUNK). LDS ~36.8 KB -> 4 blocks/CU.
// ---------------------------------------------------------------------------
__global__ void __launch_bounds__(256) kD(const bf16* __restrict__ attn, const float* __restrict__ xv,
                                          float* __restrict__ pooled,
                                          float* __restrict__ Pm, float* __restrict__ Ps)
{
    __shared__ float s1t[64][68];   // [row][r]
    __shared__ float xvt[64][68];   // [row][d]
    __shared__ float pm[4][64], ps[4][64];

    const int t = threadIdx.x, lane = t & 63, w = t >> 6;
    const int bh = blockIdx.x, chunk = blockIdx.y;
    const int b = bh >> 2, h = bh & 3;
    const int rows = NN / NCHUNK;      // 256
    const int n0 = chunk * rows;
    const int tr = t >> 4, tc = t & 15;
    const int r0 = tr * 4, d0 = tc * 4;

    float acc[4][4];
    #pragma unroll
    for(int ri = 0; ri < 4; ri++)
        #pragma unroll
        for(int ci = 0; ci < 4; ci++) acc[ri][ci] = 0.f;

    float mc = -1e30f, sc = 0.f;

    for(int st = 0; st < rows/64; st++){
        int nst = n0 + st*64;
        {
            #pragma unroll
            for(int ii = 0; ii < 4; ii++){
                int g = t + 256*ii;
                int row = g >> 4, c4 = g & 15;
                float4 v = ((const float4*)xv)[(size_t)(b*NN + nst + row)*64 + h*16 + c4];
                *(float4*)&xvt[row][c4*4] = v;
            }
        }
        // row softmax; stash logits for batched column-stat merge
        float Lr[16];
        #pragma unroll 4
        for(int i = 0; i < 16; i++){
            int lrow = w*16 + i;
            int n = nst + lrow;
            float L = b2f(attn[(size_t)(((size_t)b*NN + n)*HEAD + h)*RANK + lane]);
            float mx = wave_max64(L);
            float e  = __expf(L - mx);
            float ss = wave_sum64(e);
            s1t[lrow][lane] = e / ss;
            Lr[i] = L;
        }
        // batched merge of per-column (lane=r) stats: one rescale per subtile
        {
            float m16 = Lr[0];
            #pragma unroll
            for(int i = 1; i < 16; i++) m16 = fmaxf(m16, Lr[i]);
            float nm = fmaxf(mc, m16);
            float add = 0.f;
            #pragma unroll
            for(int i = 0; i < 16; i++) add += __expf(Lr[i] - nm);
            sc = sc * __expf(mc - nm) + add;
            mc = nm;
        }
        __syncthreads();
        for(int k = 0; k < 64; k += 4){
            #pragma unroll
            for(int kk = 0; kk < 4; kk++){
                float4 a4 = *(const float4*)&s1t[k+kk][r0];
                float4 b4 = *(const float4*)&xvt[k+kk][d0];
                float aa[4] = {a4.x,a4.y,a4.z,a4.w};
                float bb[4] = {b4.x,b4.y,b4.z,b4.w};
                #pragma unroll
                for(int ri = 0; ri < 4; ri++)
                    #pragma unroll
                    for(int ci = 0; ci < 4; ci++)
                        acc[ri][ci] = fmaf(aa[ri], bb[ci], acc[ri][ci]);
            }
        }
        __syncthreads();
    }

    #pragma unroll
    for(int ri = 0; ri < 4; ri++)
        #pragma unroll
        for(int ci = 0; ci < 4; ci++)
            atomicAdd(&pooled[(size_t)(((size_t)b*RANK + r0+ri)*HEAD + h)*HD + d0+ci], acc[ri][ci]);

    pm[w][lane] = mc; ps[w][lane] = sc;
    __syncthreads();
    if(t < 64){
        float M = pm[0][t], S = ps[0][t];
        #pragma unroll
        for(int i = 1; i < 4; i++){
            float m2 = pm[i][t], s2 = ps[i][t];
            float nm = fmaxf(M, m2);
            S = S * __expf(M - nm) + s2 * __expf(m2 - nm);
            M = nm;
        }
        Pm[(size_t)(bh*NCHUNK + chunk)*64 + t] = M;
        Ps[(size_t)(bh*NCHUNK + chunk)*64 + t] = S;
    }
}

// kC: combine chunk partials -> M,S per (b,h,r). grid 8 x 256.
__global__ void __launch_bounds__(256) kC(const float* __restrict__ Pm, const float* __restrict__ Ps,
                                          float* __restrict__ M, float* __restrict__ S)
{
    int o = blockIdx.x*256 + threadIdx.x;
    int bh = o >> 6, r = o & 63;
    float m = -1e30f, s = 0.f;
    for(int c = 0; c < NCHUNK; c++){
        float m2 = Pm[(size_t)(bh*NCHUNK + c)*64 + r];
        float s2 = Ps[(size_t)(bh*NCHUNK + c)*64 + r];
        float nm = fmaxf(m, m2);
        s = s * __expf(m - nm) + s2 * __expf(m2 - nm);
        m = nm;
    }
    M[o] = m; S[o] = s;
}

// ---------------------------------------------------------------------------
// kE: per block (bh, chunk of 128 rows): stage pooled[b,:,h,:];
//   s2 = exp(attn - M)/S; v = s2 @ pooled; out = sa*xv + sb*v.
// grid (32, ECHUNK). LDS ~34.8 KB -> 4 blocks/CU.
// ---------------------------------------------------------------------------
__global__ void __launch_bounds__(256) kE(const bf16* __restrict__ attn, const float* __restrict__ xvin,
                                          const float* __restrict__ pooled,
                                          const float* __restrict__ M, const float* __restrict__ S,
                                          const float* __restrict__ alpha, const float* __restrict__ beta,
                                          float* __restrict__ out)
{
    __shared__ float pooled_s[64][68];  // [r][d]
    __shared__ float s2t[64][68];       // [row][r]

    const int t = threadIdx.x, lane = t & 63, w = t >> 6;
    const int bh = blockIdx.x, chunk = blockIdx.y;
    const int b = bh >> 2, h = bh & 3;
    const int rows = NN / ECHUNK;      // 128
    const int n0 = chunk * rows;
    const int tr = t >> 4, tc = t & 15;
    const int row0 = tr * 4, d0 = tc * 4;

    {
        #pragma unroll
        for(int ii = 0; ii < 4; ii++){
            int g = t + 256*ii;
            int r = g >> 4, c4 = g & 15;
            float4 v = ((const float4*)pooled)[(size_t)((b*RANK + r)*HEAD + h)*16 + c4];
            *(float4*)&pooled_s[r][c4*4] = v;
        }
    }
    const float Mv   = M[bh*64 + lane];
    const float invS = 1.f / S[bh*64 + lane];
    const float sa = 1.f / (1.f + __expf(-alpha[h]));
    const float sb = 1.f / (1.f + __expf(-beta[h]));
    __syncthreads();

    for(int st = 0; st < rows/64; st++){
        int nst = n0 + st*64;
        #pragma unroll 4
        for(int i = 0; i < 16; i++){
            int lrow = w*16 + i;
            int n = nst + lrow;
            float L = b2f(attn[(size_t)(((size_t)b*NN + n)*HEAD + h)*RANK + lane]);
            s2t[lrow][lane] = __expf(L - Mv) * invS;
        }
        __syncthreads();
        float acc[4][4];
        #pragma unroll
        for(int ri = 0; ri < 4; ri++)
            #pragma unroll
            for(int ci = 0; ci < 4; ci++) acc[ri][ci] = 0.f;
        for(int k = 0; k < 64; k += 4){
            float4 a4[4];
            #pragma unroll
            for(int ri = 0; ri < 4; ri++) a4[ri] = *(const float4*)&s2t[row0+ri][k];
            #pragma unroll
            for(int kk = 0; kk < 4; kk++){
                float4 b4 = *(const float4*)&pooled_s[k+kk][d0];
                float bb[4] = {b4.x,b4.y,b4.z,b4.w};
                #pragma unroll
                for(int ri = 0; ri < 4; ri++){
                    float av = (kk==0)?a4[ri].x:(kk==1)?a4[ri].y:(kk==2)?a4[ri].z:a4[ri].w;
                    #pragma unroll
                    for(int ci = 0; ci < 4; ci++)
                        acc[ri][ci] = fmaf(av, bb[ci], acc[ri][ci]);
                }
            }
        }
        #pragma unroll
        for(int ri = 0; ri < 4; ri++){
            int n = nst + row0 + ri;
            size_t g4 = (size_t)(b*NN + n)*64 + h*16 + tc;
            float4 xv4 = ((const float4*)xvin)[g4];
            float4 o4;
            o4.x = sa*xv4.x + sb*acc[ri][0];
            o4.y = sa*xv4.y + sb*acc[ri][1];
            o4.z = sa*xv4.z + sb*acc[ri][2];
            o4.w = sa*xv4.w + sb*acc[ri][3];
            ((float4*)out)[g4] = o4;
        }
        __syncthreads();
    }
}

extern "C" void kernel_launch(void* const* d_in, const int* in_sizes, int n_in,
                              void* d_out, int out_size, void* d_ws, size_t ws_size,
                              hipStream_t stream)
{
    (void)in_sizes; (void)n_in; (void)out_size; (void)ws_size;
    const float* x     = (const float*)d_in[0];
    const float* z     = (const float*)d_in[1];
    const float* Wq    = (const float*)d_in[2];
    const float* bq    = (const float*)d_in[3];
    const float* Km    = (const float*)d_in[4];
    const float* Wv    = (const float*)d_in[5];
    const float* bv    = (const float*)d_in[6];
    const float* alpha = (const float*)d_in[7];
    const float* beta  = (const float*)d_in[8];
    float* out = (float*)d_out;

    // xv (fp32) lives in d_out: kA2 writes it, kD reads it, kE reads element i
    // and overwrites out[i] in the same thread (no cross-thread hazard).
    float* xv = out;

    char* ws = (char*)d_ws;
    bf16*  attn   = (bf16*)(ws + 0);                          // 33,554,432 B
    float* pooled = (float*)(ws + 33554432);                  // 524,288 B
    float* Mst    = (float*)(ws + 34078720);                  // 8,192 B
    float* Sst    = (float*)(ws + 34086912);                  // 8,192 B
    float* Pm     = (float*)(ws + 34095104);                  // 262,144 B
    float* Ps     = (float*)(ws + 34357248);                  // 262,144 B
    unsigned short* WattnT = (unsigned short*)(ws + 34619392); // 131,072 B
    unsigned short* WvT    = (unsigned short*)(ws + 34750464); // 131,072 B
    float* battn  = (float*)(ws + 34881536);                  // 1,024 B
                                                              // total: 34,882,560 B

    (void)hipMemsetAsync(pooled, 0, 524288, stream);
    kW<<<dim3(256), 256, 0, stream>>>(Wq, bq, Km, Wv, WattnT, WvT, battn);
    kA2<<<dim3(BN/64), 256, 0, stream>>>(x, WvT, bv, xv, nullptr, 0);
    kA2<<<dim3(BN/64), 256, 0, stream>>>(z, WattnT, battn, nullptr, attn, 1);
    kD<<<dim3(32, NCHUNK), 256, 0, stream>>>(attn, xv, pooled, Pm, Ps);
    kC<<<dim3(8), 256, 0, stream>>>(Pm, Ps, Mst, Sst);
    kE<<<dim3(32, ECHUNK), 256, 0, stream>>>(attn, xv, pooled, Mst, Sst, alpha, beta, out);
}

// Round 8
// 294.597 us; speedup vs baseline: 4.5858x; 1.3514x over previous
//
#include <hip/hip_runtime.h>
#include <hip/hip_bf16.h>

typedef __hip_bfloat16 bf16;
typedef __attribute__((ext_vector_type(8))) __bf16 bf16x8;
typedef __attribute__((ext_vector_type(4))) float f32x4;

#define BB 8
#define NN 8192
#define DIM 256
#define HEAD 4
#define HD 64
#define RANK 64
#define BN (BB*NN)

__device__ __forceinline__ float b2f(bf16 v){ return __bfloat162float(v); }
__device__ __forceinline__ bf16 f2b(float v){ return __float2bfloat16(v); }
__device__ __forceinline__ unsigned short f2bu(float f){
    bf16 h = __float2bfloat16(f);
    return *(unsigned short*)&h;
}
__device__ __forceinline__ float u2f(unsigned short u){
    unsigned int x = ((unsigned int)u) << 16; return __uint_as_float(x);
}
__device__ __forceinline__ __bf16 f2bb(float f){
    bf16 h = __float2bfloat16(f);
    return *reinterpret_cast<__bf16*>(&h);
}
// physical position of (outer, k) in a chunk-swizzled [outer][K] bf16 LDS tile
__device__ __forceinline__ int swz(int k, int outer){
    return (((k >> 3) ^ (outer & 7)) << 3) | (k & 7);
}

// ---------------------------------------------------------------------------
// kW: precompute WattnT[c][f] (K folded, /8 folded), WvT[c][f], battn[c].
// ---------------------------------------------------------------------------
__global__ void __launch_bounds__(256) kW(
    const float* __restrict__ Wq, const float* __restrict__ bq,
    const float* __restrict__ Km, const float* __restrict__ Wv,
    unsigned short* __restrict__ WattnT, unsigned short* __restrict__ WvT,
    float* __restrict__ battn)
{
    const int c = blockIdx.x;       // output col = h*64+r
    const int h = c >> 6, r = c & 63;
    const int t = threadIdx.x;      // f
    __shared__ float Ks[64];
    if(t < 64) Ks[t] = Km[((size_t)r*HEAD + h)*64 + t];
    __syncthreads();

    const float* wqrow = Wq + (size_t)t*DIM + h*64;
    float a = 0.f;
    #pragma unroll
    for(int d = 0; d < 64; d++) a = fmaf(wqrow[d], Ks[d], a);
    WattnT[(size_t)c*DIM + t] = f2bu(0.125f * a);
    WvT[(size_t)c*DIM + t]    = f2bu(Wv[(size_t)t*DIM + c]);
    if(t == 0){
        float bb = 0.f;
        for(int d = 0; d < 64; d++) bb += bq[h*64+d]*Ks[d];
        battn[c] = 0.125f * bb;
    }
}

// ---------------------------------------------------------------------------
// kA2: MFMA GEMM OUT[64 x 256] = A @ W^T + bias.
//   bf16out=0: fp32 -> outF[bn][256] (xv)
//   bf16out=1: bf16 -> attn[b][h][n][r] + per-block column stats -> Pm/Ps
// ---------------------------------------------------------------------------
__global__ void __launch_bounds__(256) kA2(
    const float* __restrict__ A, const unsigned short* __restrict__ WT,
    const float* __restrict__ bias,
    float* __restrict__ outF, unsigned short* __restrict__ outB,
    float* __restrict__ Pm, float* __restrict__ Ps, const int bf16out)
{
    __shared__ __attribute__((aligned(16))) __bf16 As[64][40];   // rows x k-slab (pad 40)
    __shared__ __attribute__((aligned(16))) __bf16 Ws[256][40];  // cols(n) x k-slab

    const int t    = threadIdx.x;
    const int lane = t & 63;
    const int w    = t >> 6;
    const int q    = lane >> 4;
    const int l15  = lane & 15;
    const int brow = blockIdx.x * 64;

    f32x4 acc[4][4];
    #pragma unroll
    for(int tm = 0; tm < 4; tm++)
        #pragma unroll
        for(int tn = 0; tn < 4; tn++) acc[tm][tn] = (f32x4){0.f,0.f,0.f,0.f};

    const int arow = t >> 2, aseg = t & 3;

    for(int k0 = 0; k0 < DIM; k0 += 32){
        {
            const float* ap = A + (size_t)(brow + arow)*DIM + k0 + aseg*8;
            float4 v0 = *(const float4*)(ap + 0);
            float4 v1 = *(const float4*)(ap + 4);
            __attribute__((aligned(16))) __bf16 tmp[8] = {
                f2bb(v0.x), f2bb(v0.y), f2bb(v0.z), f2bb(v0.w),
                f2bb(v1.x), f2bb(v1.y), f2bb(v1.z), f2bb(v1.w)};
            *(bf16x8*)&As[arow][aseg*8] = *(bf16x8*)tmp;
        }
        #pragma unroll
        for(int ii = 0; ii < 4; ii++){
            int c = t + 256*ii;
            int n = c >> 2, seg = c & 3;
            uint4 wv = *(const uint4*)(WT + (size_t)n*DIM + k0 + seg*8);
            *(uint4*)&Ws[n][seg*8] = wv;
        }
        __syncthreads();

        bf16x8 af[4], bf[4];
        #pragma unroll
        for(int tm = 0; tm < 4; tm++) af[tm] = *(const bf16x8*)&As[tm*16 + l15][q*8];
        #pragma unroll
        for(int tn = 0; tn < 4; tn++) bf[tn] = *(const bf16x8*)&Ws[w*64 + tn*16 + l15][q*8];
        #pragma unroll
        for(int tm = 0; tm < 4; tm++)
            #pragma unroll
            for(int tn = 0; tn < 4; tn++)
                acc[tm][tn] = __builtin_amdgcn_mfma_f32_16x16x32_bf16(
                    af[tm], bf[tn], acc[tm][tn], 0, 0, 0);
        __syncthreads();
    }

    if(bf16out){
        const int b  = brow >> 13;
        const int nb = brow & 8191;
        const size_t blk = blockIdx.x;
        #pragma unroll
        for(int tn = 0; tn < 4; tn++){
            int col = w*64 + tn*16 + l15;
            int hh = col >> 6, rr = col & 63;
            float bcol = bias[col];
            float rv[16];
            float m16 = -1e30f;
            #pragma unroll
            for(int tm = 0; tm < 4; tm++){
                #pragma unroll
                for(int reg = 0; reg < 4; reg++){
                    float v = acc[tm][tn][reg] + bcol;
                    unsigned short ub = f2bu(v);
                    int n = nb + tm*16 + q*4 + reg;
                    outB[(((size_t)(b*HEAD + hh))*NN + n)*64 + rr] = ub;
                    float vr = u2f(ub);
                    rv[tm*4+reg] = vr;
                    m16 = fmaxf(m16, vr);
                }
            }
            float s16 = 0.f;
            #pragma unroll
            for(int i = 0; i < 16; i++) s16 += __expf(rv[i] - m16);
            // merge across quads (same col on lanes l15, +16, +32, +48)
            #pragma unroll
            for(int off = 16; off <= 32; off <<= 1){
                float m2 = __shfl_xor(m16, off, 64);
                float s2 = __shfl_xor(s16, off, 64);
                float nm = fmaxf(m16, m2);
                s16 = s16*__expf(m16-nm) + s2*__expf(m2-nm);
                m16 = nm;
            }
            if(q == 0){
                Pm[blk*256 + col] = m16;
                Ps[blk*256 + col] = s16;
            }
        }
    } else {
        #pragma unroll
        for(int tn = 0; tn < 4; tn++){
            int col = w*64 + tn*16 + l15;
            float bcol = bias[col];
            #pragma unroll
            for(int tm = 0; tm < 4; tm++){
                #pragma unroll
                for(int reg = 0; reg < 4; reg++){
                    int grow = brow + tm*16 + q*4 + reg;
                    outF[(size_t)grow*256 + col] = acc[tm][tn][reg] + bcol;
                }
            }
        }
    }
}

// ---------------------------------------------------------------------------
// kC: merge per-block stats -> M,S per (b, col). grid 8 x 256.
// ---------------------------------------------------------------------------
__global__ void __launch_bounds__(256) kC(const float* __restrict__ Pm, const float* __restrict__ Ps,
                                          float* __restrict__ M, float* __restrict__ S)
{
    const int b = blockIdx.x, col = threadIdx.x;
    float m = -1e30f;
    for(int c = 0; c < 128; c++)
        m = fmaxf(m, Pm[(size_t)(b*128 + c)*256 + col]);
    float s = 0.f;
    for(int c = 0; c < 128; c++){
        size_t i = (size_t)(b*128 + c)*256 + col;
        s += Ps[i] * __expf(Pm[i] - m);
    }
    M[b*256 + col] = m;
    S[b*256 + col] = s;
}

// ---------------------------------------------------------------------------
// kD: per block (bh, 256-row chunk): thread owns a row; in-register row
//   softmax; LDS-transposed bf16 operands; MFMA pooledT[d][r] += ...
//   (1/rowsum folded into the xv operand). grid (32, 32). LDS 64 KB.
// ---------------------------------------------------------------------------
__global__ void __launch_bounds__(256) kD(const unsigned short* __restrict__ attn,
                                          const float* __restrict__ xv,
                                          float* __restrict__ pooledT)
{
    __shared__ unsigned short s1T[64*256];  // [r][row] swizzled: raw exp(L - rowmax)
    __shared__ unsigned short xvT[64*256];  // [d][row] swizzled: xv / rowsum

    const int t = threadIdx.x, lane = t & 63, w = t >> 6;
    const int bh = blockIdx.x, chunk = blockIdx.y;
    const int b = bh >> 2, h = bh & 3;
    const int n0 = chunk * 256;
    const int row = t;

    // ---- phase 1: row softmax + transposed staging ----
    {
        const uint4* ap = (const uint4*)(attn + ((size_t)bh*NN + n0 + row)*64);
        uint4 ar[8];
        #pragma unroll
        for(int c = 0; c < 8; c++) ar[c] = ap[c];
        float vals[64];
        #pragma unroll
        for(int c = 0; c < 8; c++){
            unsigned int uu[4] = {ar[c].x, ar[c].y, ar[c].z, ar[c].w};
            #pragma unroll
            for(int p = 0; p < 4; p++){
                vals[c*8 + p*2 + 0] = __uint_as_float(uu[p] << 16);
                vals[c*8 + p*2 + 1] = __uint_as_float(uu[p] & 0xffff0000u);
            }
        }
        float mx = -1e30f;
        #pragma unroll
        for(int r = 0; r < 64; r++) mx = fmaxf(mx, vals[r]);
        float s = 0.f;
        #pragma unroll
        for(int r = 0; r < 64; r++){
            float e = __expf(vals[r] - mx);
            s += e;
            s1T[r*256 + swz(row, r)] = f2bu(e);
        }
        float rs = 1.f / s;
        const float4* xp = (const float4*)(xv + ((size_t)(b*NN + n0 + row))*256 + h*64);
        #pragma unroll
        for(int c = 0; c < 16; c++){
            float4 f = xp[c];
            int d0 = c*4;
            xvT[(d0+0)*256 + swz(row, d0+0)] = f2bu(f.x * rs);
            xvT[(d0+1)*256 + swz(row, d0+1)] = f2bu(f.y * rs);
            xvT[(d0+2)*256 + swz(row, d0+2)] = f2bu(f.z * rs);
            xvT[(d0+3)*256 + swz(row, d0+3)] = f2bu(f.w * rs);
        }
    }
    __syncthreads();

    // ---- phase 2: MFMA pooledT[d][r] = sum_row xvT . s1T ----
    const int q = lane >> 4, l15 = lane & 15;
    const int dm = w*16 + l15;   // a-frag outer (d)
    f32x4 acc[4];
    #pragma unroll
    for(int tn = 0; tn < 4; tn++) acc[tn] = (f32x4){0.f,0.f,0.f,0.f};

    #pragma unroll
    for(int slab = 0; slab < 8; slab++){
        int c = slab*4 + q;
        bf16x8 a = *(const bf16x8*)&xvT[dm*256 + ((c ^ (dm & 7))<<3)];
        #pragma unroll
        for(int tn = 0; tn < 4; tn++){
            int rn = tn*16 + l15;
            bf16x8 bb = *(const bf16x8*)&s1T[rn*256 + ((c ^ (rn & 7))<<3)];
            acc[tn] = __builtin_amdgcn_mfma_f32_16x16x32_bf16(a, bb, acc[tn], 0, 0, 0);
        }
    }
    #pragma unroll
    for(int tn = 0; tn < 4; tn++){
        #pragma unroll
        for(int reg = 0; reg < 4; reg++){
            int d = w*16 + q*4 + reg;
            int r = tn*16 + l15;
            atomicAdd(&pooledT[((size_t)bh*64 + d)*64 + r], acc[tn][reg]);
        }
    }
}

// ---------------------------------------------------------------------------
// kE: per block (bh, 256-row chunk): thread owns a row; s2 from M/S (LDS
//   broadcast); MFMA v = s2t @ pooledT; out = sa*xv + sb*v. grid (32, 32).
// ---------------------------------------------------------------------------
__global__ void __launch_bounds__(256) kE(const unsigned short* __restrict__ attn,
                                          const float* __restrict__ xvin,
                                          const float* __restrict__ pooledT,
                                          const float* __restrict__ Mst, const float* __restrict__ Sst,
                                          const float* __restrict__ alpha, const float* __restrict__ beta,
                                          float* __restrict__ out)
{
    __shared__ unsigned short s2t[256*64];  // [row][r] swizzled
    __shared__ unsigned short plT[64*64];   // [d][r] swizzled
    __shared__ float Ms[64], Sinv[64];

    const int t = threadIdx.x, lane = t & 63, w = t >> 6;
    const int bh = blockIdx.x, chunk = blockIdx.y;
    const int b = bh >> 2, h = bh & 3;
    const int n0 = chunk * 256;
    const int row = t;

    if(t < 64){
        Ms[t]   = Mst[b*256 + h*64 + t];
        Sinv[t] = 1.f / Sst[b*256 + h*64 + t];
    }
    // stage pooledT -> bf16 LDS [d][r]
    {
        int d = t >> 2, seg = t & 3;
        const float4* pp = (const float4*)(pooledT + ((size_t)bh*64 + d)*64 + seg*16);
        float4 p0 = pp[0], p1 = pp[1], p2 = pp[2], p3 = pp[3];
        __attribute__((aligned(16))) unsigned short tmp[16] = {
            f2bu(p0.x),f2bu(p0.y),f2bu(p0.z),f2bu(p0.w),
            f2bu(p1.x),f2bu(p1.y),f2bu(p1.z),f2bu(p1.w),
            f2bu(p2.x),f2bu(p2.y),f2bu(p2.z),f2bu(p2.w),
            f2bu(p3.x),f2bu(p3.y),f2bu(p3.z),f2bu(p3.w)};
        int c0 = seg*2;
        *(uint4*)&plT[d*64 + (((c0+0) ^ (d&7))<<3)] = *(uint4*)&tmp[0];
        *(uint4*)&plT[d*64 + (((c0+1) ^ (d&7))<<3)] = *(uint4*)&tmp[8];
    }
    __syncthreads();

    // ---- phase 1: s2 rows ----
    {
        const uint4* ap = (const uint4*)(attn + ((size_t)bh*NN + n0 + row)*64);
        #pragma unroll
        for(int c = 0; c < 8; c++){
            uint4 u = ap[c];
            unsigned int uu[4] = {u.x, u.y, u.z, u.w};
            unsigned int ov[4];
            #pragma unroll
            for(int p = 0; p < 4; p++){
                int r = c*8 + p*2;
                float v0 = __uint_as_float(uu[p] << 16);
                float v1 = __uint_as_float(uu[p] & 0xffff0000u);
                float e0 = __expf(v0 - Ms[r])   * Sinv[r];
                float e1 = __expf(v1 - Ms[r+1]) * Sinv[r+1];
                ov[p] = (unsigned int)f2bu(e0) | ((unsigned int)f2bu(e1) << 16);
            }
            uint4 w4; w4.x = ov[0]; w4.y = ov[1]; w4.z = ov[2]; w4.w = ov[3];
            *(uint4*)&s2t[row*64 + ((c ^ (row&7))<<3)] = w4;
        }
    }
    __syncthreads();

    // ---- phase 2: MFMA v[row][d] = sum_r s2t . plT ----
    const int q = lane >> 4, l15 = lane & 15;
    f32x4 acc[4][4];
    #pragma unroll
    for(int tm = 0; tm < 4; tm++)
        #pragma unroll
        for(int tn = 0; tn < 4; tn++) acc[tm][tn] = (f32x4){0.f,0.f,0.f,0.f};

    #pragma unroll
    for(int s = 0; s < 2; s++){
        int c = s*4 + q;
        bf16x8 bfr[4], af[4];
        #pragma unroll
        for(int tn = 0; tn < 4; tn++){
            int dn = tn*16 + l15;
            bfr[tn] = *(const bf16x8*)&plT[dn*64 + ((c ^ (dn&7))<<3)];
        }
        #pragma unroll
        for(int tm = 0; tm < 4; tm++){
            int ra = w*64 + tm*16 + l15;
            af[tm] = *(const bf16x8*)&s2t[ra*64 + ((c ^ (ra&7))<<3)];
        }
        #pragma unroll
        for(int tm = 0; tm < 4; tm++)
            #pragma unroll
            for(int tn = 0; tn < 4; tn++)
                acc[tm][tn] = __builtin_amdgcn_mfma_f32_16x16x32_bf16(
                    af[tm], bfr[tn], acc[tm][tn], 0, 0, 0);
    }

    const float sa = 1.f / (1.f + __expf(-alpha[h]));
    const float sb = 1.f / (1.f + __expf(-beta[h]));
    #pragma unroll
    for(int tm = 0; tm < 4; tm++){
        #pragma unroll
        for(int reg = 0; reg < 4; reg++){
            int rowo = w*64 + tm*16 + q*4 + reg;
            size_t gbase = ((size_t)(b*NN + n0 + rowo))*256 + h*64;
            #pragma unroll
            for(int tn = 0; tn < 4; tn++){
                int d = tn*16 + l15;
                out[gbase + d] = sa*xvin[gbase + d] + sb*acc[tm][tn][reg];
            }
        }
    }
}

extern "C" void kernel_launch(void* const* d_in, const int* in_sizes, int n_in,
                              void* d_out, int out_size, void* d_ws, size_t ws_size,
                              hipStream_t stream)
{
    (void)in_sizes; (void)n_in; (void)out_size; (void)ws_size;
    const float* x     = (const float*)d_in[0];
    const float* z     = (const float*)d_in[1];
    const float* Wq    = (const float*)d_in[2];
    const float* bq    = (const float*)d_in[3];
    const float* Km    = (const float*)d_in[4];
    const float* Wv    = (const float*)d_in[5];
    const float* bv    = (const float*)d_in[6];
    const float* alpha = (const float*)d_in[7];
    const float* beta  = (const float*)d_in[8];
    float* out = (float*)d_out;

    // xv fp32 lives in d_out: kA2 writes, kD/kE read, kE overwrites out[i]
    // in the same thread that read xv[i].
    float* xv = out;

    char* ws = (char*)d_ws;
    unsigned short* attn  = (unsigned short*)(ws + 0);         // 33,554,432 B  [b][h][n][r]
    float* pooledT = (float*)(ws + 33554432);                  // 524,288 B    [bh][d][r]
    float* Mst     = (float*)(ws + 34078720);                  // 8,192 B      [b][col]
    float* Sst     = (float*)(ws + 34086912);                  // 8,192 B
    float* Pm      = (float*)(ws + 34095104);                  // 1,048,576 B  [1024][256]
    float* Ps      = (float*)(ws + 35143680);                  // 1,048,576 B
    unsigned short* WattnT = (unsigned short*)(ws + 36192256); // 131,072 B
    unsigned short* WvT    = (unsigned short*)(ws + 36323328); // 131,072 B
    float* battn   = (float*)(ws + 36454400);                  // 1,024 B
                                                               // total: 36,455,424 B

    (void)hipMemsetAsync(pooledT, 0, 524288, stream);
    kW<<<dim3(256), 256, 0, stream>>>(Wq, bq, Km, Wv, WattnT, WvT, battn);
    kA2<<<dim3(BN/64), 256, 0, stream>>>(x, WvT, bv, xv, nullptr, nullptr, nullptr, 0);
    kA2<<<dim3(BN/64), 256, 0, stream>>>(z, WattnT, battn, nullptr, attn, Pm, Ps, 1);
    kC<<<dim3(8), 256, 0, stream>>>(Pm, Ps, Mst, Sst);
    kD<<<dim3(32, 32), 256, 0, stream>>>(attn, xv, pooledT);
    kE<<<dim3(32, 32), 256, 0, stream>>>(attn, xv, pooledT, Mst, Sst, alpha, beta, out);
}